// Round 6
// baseline (124.603 us; speedup 1.0000x reference)
//
#include <hip/hip_runtime.h>
#include <hip/hip_bf16.h>

#define B_ 4
#define S_ 4096
#define DM 1024
#define H_ 16
#define HD 64
#define BH (B_*H_)
#define SPLIT 8
#define CHUNK (S_/SPLIT)   // 512
#define SUB 64             // s-rows per staged buffer

typedef __attribute__((ext_vector_type(8))) __bf16 bf16x8;
typedef __attribute__((ext_vector_type(4))) __bf16 bf16x4;
typedef __attribute__((ext_vector_type(4))) float f32x4;

#define MFMA16(a,b,c) __builtin_amdgcn_mfma_f32_16x16x32_bf16((a),(b),(c),0,0,0)

__device__ __forceinline__ void gload_lds16(const void* g, void* l) {
  __builtin_amdgcn_global_load_lds(
      (const __attribute__((address_space(1))) void*)g,
      (__attribute__((address_space(3))) void*)l, 16, 0, 0);
}

// ---------------------------------------------------------------------------
// K0q: Q f32 -> bf16 streaming cast.
// 4096 blocks x 256 thr; 1,048,576 threads; 4 f32x4 each; stride = #threads.
// (round-5 bug: stride was 4194304 = TOTAL count -> 3.25x OOB -> abort)
// ---------------------------------------------------------------------------
__global__ __launch_bounds__(256)
void k0_convq(const float* __restrict__ Qg, __bf16* __restrict__ Qb) {
  const size_t t = (size_t)blockIdx.x * 256 + threadIdx.x;
#pragma unroll
  for (int it = 0; it < 4; ++it) {
    const size_t i = (size_t)it * 1048576 + t;   // 4,194,304 f32x4 total
    f32x4 w = *reinterpret_cast<const f32x4*>(Qg + i * 4);
    bf16x4 o;
#pragma unroll
    for (int j = 0; j < 4; ++j) o[j] = (__bf16)w[j];
    *reinterpret_cast<bf16x4*>(Qb + i * 4) = o;
  }
}

// ---------------------------------------------------------------------------
// K1 v2: partial KV[split][bh][d][e] = sum_s K[s][d]*V[s][e], pure f32 VALU.
// grid = SPLIT*BH = 512 blocks (2/CU), 256 threads.
// K,V staged f32 LINEAR via global_load_lds (deep queue), double-buffered
// (T3-minimum: raw s_barrier + asm vmcnt). Thread owns 4x4 f32 acc.
// No transpose, no conversion, no bank conflicts.
// ---------------------------------------------------------------------------
__global__ __launch_bounds__(256)
void k1_kv(const float* __restrict__ Kg, const float* __restrict__ Vg,
           float* __restrict__ partial) {
  __shared__ __align__(16) float Kb[2][SUB][64];   // 32 KiB
  __shared__ __align__(16) float Vb[2][SUB][64];   // 32 KiB
  const int bid = blockIdx.x;
  const int split = bid >> 6, bh = bid & 63;
  const int b = bh >> 4, h = bh & 15;
  const int t = threadIdx.x, wid = t >> 6;
  const int s0 = split * CHUNK;
  const float* Ksrc = Kg + ((size_t)b * S_ + s0) * DM + h * HD;
  const float* Vsrc = Vg + ((size_t)b * S_ + s0) * DM + h * HD;
  const int d0 = (t >> 4) * 4, e0 = (t & 15) * 4;
  float acc[4][4] = {};

  auto stage = [&](int bi, int sc) {
    const char* Kp = (const char*)(Ksrc + (size_t)sc * SUB * DM);
    const char* Vp = (const char*)(Vsrc + (size_t)sc * SUB * DM);
#pragma unroll
    for (int it = 0; it < 4; ++it) {
      const int idx = it * 256 + t;
      const int row = idx >> 4, ch = idx & 15;       // 64 rows x 16 chunks(16B)
      const int ldso = (it * 256 + wid * 64) * 16;   // wave-uniform base
      gload_lds16((const void*)(Kp + (size_t)row * (DM * 4) + ch * 16),
                  (void*)((char*)&Kb[bi][0][0] + ldso));
      gload_lds16((const void*)(Vp + (size_t)row * (DM * 4) + ch * 16),
                  (void*)((char*)&Vb[bi][0][0] + ldso));
    }
  };

  stage(0, 0);
  asm volatile("s_waitcnt vmcnt(0)" ::: "memory");
  __builtin_amdgcn_s_barrier();

  for (int hc = 0; hc < CHUNK / SUB; ++hc) {
    const int cur = hc & 1;
    if (hc + 1 < CHUNK / SUB) stage(cur ^ 1, hc + 1);   // prefetch overlaps compute
    const float* Ks = &Kb[cur][0][0];
    const float* Vs = &Vb[cur][0][0];
#pragma unroll 8
    for (int s = 0; s < SUB; ++s) {
      f32x4 kv = *reinterpret_cast<const f32x4*>(Ks + s * 64 + d0);
      f32x4 vv = *reinterpret_cast<const f32x4*>(Vs + s * 64 + e0);
#pragma unroll
      for (int i = 0; i < 4; ++i)
#pragma unroll
        for (int j = 0; j < 4; ++j)
          acc[i][j] = fmaf(kv[i], vv[j], acc[i][j]);
    }
    asm volatile("s_waitcnt vmcnt(0)" ::: "memory");
    __builtin_amdgcn_s_barrier();
  }

  float* dst = partial + ((size_t)(split * BH + bh) << 12);
#pragma unroll
  for (int i = 0; i < 4; ++i) {
    f32x4 o;
#pragma unroll
    for (int j = 0; j < 4; ++j) o[j] = acc[i][j];
    *reinterpret_cast<f32x4*>(dst + (d0 + i) * 64 + e0) = o;
  }
}

// ---------------------------------------------------------------------------
// K2: reduce 8 partials -> kvt[bh][d][e] bf16.  grid = BH*4 = 256 blocks.
// ---------------------------------------------------------------------------
__global__ __launch_bounds__(256)
void k2_kv_reduce(const float* __restrict__ partial,
                  __bf16* __restrict__ kvt) {
  const int bid = blockIdx.x;
  const int bh = bid >> 2, q = bid & 3;
  const int t = threadIdx.x;
#pragma unroll
  for (int i = 0; i < 4; ++i) {
    const int idx = q * 1024 + i * 256 + t;   // d*64+e
    float s = 0.f;
#pragma unroll
    for (int sp = 0; sp < SPLIT; ++sp)
      s += partial[((size_t)(sp * BH + bh) << 12) + idx];
    kvt[((size_t)bh << 12) + idx] = (__bf16)s;
  }
}

// ---------------------------------------------------------------------------
// K2.5: Ut[b][n][h*64+d] = sum_e W[n][h*64+e] * KV[bh][d][e]   (bf16 out)
// grid = BH*4 = 256 blocks.  (unchanged, verified)
// ---------------------------------------------------------------------------
__global__ __launch_bounds__(256)
void k25_u(const float* __restrict__ Wg,
           const __bf16* __restrict__ kvt,
           __bf16* __restrict__ Ut) {
  const int bid = blockIdx.x;
  const int bh = bid >> 2, nblk = bid & 3;
  const int b = bh >> 4, h = bh & 15;
  const int t = threadIdx.x, w = t >> 6, l = t & 63, lr = l & 15, lg = l >> 4;
  const int n0w = nblk * 256 + w * 64;
  const __bf16* kvb = kvt + ((size_t)bh << 12);
  f32x4 acc[4][4] = {};
#pragma unroll
  for (int ks = 0; ks < 2; ++ks) {
    bf16x8 bfr[4];
#pragma unroll
    for (int nf = 0; nf < 4; ++nf)
      bfr[nf] = *reinterpret_cast<const bf16x8*>(kvb + (nf * 16 + lr) * 64 + ks * 32 + lg * 8);
#pragma unroll
    for (int mf = 0; mf < 4; ++mf) {
      const int n = n0w + mf * 16 + lr;
      const float* wp = Wg + (size_t)n * DM + h * 64 + ks * 32 + lg * 8;
      f32x4 w0 = *reinterpret_cast<const f32x4*>(wp);
      f32x4 w1 = *reinterpret_cast<const f32x4*>(wp + 4);
      bf16x8 af;
#pragma unroll
      for (int j = 0; j < 4; ++j) { af[j] = (__bf16)w0[j]; af[4 + j] = (__bf16)w1[j]; }
#pragma unroll
      for (int nf = 0; nf < 4; ++nf)
        acc[mf][nf] = MFMA16(af, bfr[nf], acc[mf][nf]);
    }
  }
  __bf16* ub = Ut + ((size_t)b << 20);
#pragma unroll
  for (int mf = 0; mf < 4; ++mf)
#pragma unroll
    for (int nf = 0; nf < 4; ++nf)
#pragma unroll
      for (int r = 0; r < 4; ++r) {
        const int n = n0w + mf * 16 + lg * 4 + r;
        ub[(size_t)n * DM + h * 64 + nf * 16 + lr] = (__bf16)acc[mf][nf][r];
      }
}

// ---------------------------------------------------------------------------
// K4: out[b] = Qb[b] @ Ut[b]^T + bias.  4 x (M=4096, N=1024, K=1024).
// Both operands bf16 via global_load_lds w16, pre-swizzled source +
// swizzled ds_read_b128 (conflict-free).  (unchanged, verified)
// ---------------------------------------------------------------------------
__global__ __launch_bounds__(256)
void k4_out_gemm(const __bf16* __restrict__ Qb,
                 const __bf16* __restrict__ Ut,
                 const float* __restrict__ biasg,
                 float* __restrict__ outg) {
  __shared__ __align__(16) __bf16 Alds[128 * 64];
  __shared__ __align__(16) __bf16 Blds[128 * 64];
  const int bid = blockIdx.x;
  const int b = bid >> 8, rem = bid & 255;
  const int nblk = rem >> 5, mblk = rem & 31;
  const int m0 = mblk * 128, n0 = nblk * 128;
  const int t = threadIdx.x, wid = t >> 6, l = t & 63, lr = l & 15, lg = l >> 4;
  const int wr = wid >> 1, wc = wid & 1;
  const __bf16* Ab = Qb + (size_t)b * S_ * DM;
  const __bf16* Bb = Ut + ((size_t)b << 20);
  f32x4 acc[4][4] = {};

  for (int kt = 0; kt < 16; ++kt) {
    const int k0 = kt * 64;
#pragma unroll
    for (int it = 0; it < 4; ++it) {
      const int idx = it * 256 + t;
      const int row = idx >> 3, c = idx & 7;
      const int gc = c ^ (row & 7);
      gload_lds16((const void*)(Ab + (size_t)(m0 + row) * DM + k0 + gc * 8),
                  (void*)((char*)Alds + (it * 256 + wid * 64) * 16));
      gload_lds16((const void*)(Bb + (size_t)(n0 + row) * DM + k0 + gc * 8),
                  (void*)((char*)Blds + (it * 256 + wid * 64) * 16));
    }
    __syncthreads();
#pragma unroll
    for (int ks = 0; ks < 2; ++ks) {
      bf16x8 af[4], bfr[4];
#pragma unroll
      for (int mt = 0; mt < 4; ++mt) {
        const int row = wr * 64 + mt * 16 + lr;
        const int ch = (ks * 4 + lg) ^ (row & 7);
        af[mt] = *reinterpret_cast<const bf16x8*>((const char*)Alds + row * 128 + ch * 16);
      }
#pragma unroll
      for (int nt = 0; nt < 4; ++nt) {
        const int row = wc * 64 + nt * 16 + lr;
        const int ch = (ks * 4 + lg) ^ (row & 7);
        bfr[nt] = *reinterpret_cast<const bf16x8*>((const char*)Blds + row * 128 + ch * 16);
      }
#pragma unroll
      for (int mt = 0; mt < 4; ++mt)
#pragma unroll
        for (int nt = 0; nt < 4; ++nt)
          acc[mt][nt] = MFMA16(af[mt], bfr[nt], acc[mt][nt]);
    }
    __syncthreads();
  }

#pragma unroll
  for (int nt = 0; nt < 4; ++nt) {
    const int colg = n0 + wc * 64 + nt * 16 + lr;
    const float bv = biasg[colg];
#pragma unroll
    for (int mt = 0; mt < 4; ++mt)
#pragma unroll
      for (int r = 0; r < 4; ++r) {
        const int rowg = m0 + wr * 64 + mt * 16 + lg * 4 + r;
        outg[((size_t)b * S_ + rowg) * DM + colg] = acc[mt][nt][r] + bv;
      }
  }
}

extern "C" void kernel_launch(void* const* d_in, const int* in_sizes, int n_in,
                              void* d_out, int out_size, void* d_ws, size_t ws_size,
                              hipStream_t stream) {
  const float* Q = (const float*)d_in[0];
  const float* K = (const float*)d_in[1];
  const float* V = (const float*)d_in[2];
  const float* W = (const float*)d_in[3];
  const float* bias = (const float*)d_in[4];
  float* out = (float*)d_out;

  char* ws = (char*)d_ws;
  float* partial = (float*)ws;                        // 8 MiB @ 0
  __bf16* kvt = (__bf16*)(ws + (8u << 20));           // 512 KiB
  __bf16* Ut  = (__bf16*)(ws + (9u << 20));           // 8 MiB
  __bf16* Qb  = (__bf16*)(ws + (17u << 20));          // 32 MiB

  hipLaunchKernelGGL(k1_kv, dim3(SPLIT * BH), dim3(256), 0, stream, K, V, partial);
  hipLaunchKernelGGL(k0_convq, dim3(4096), dim3(256), 0, stream, Q, Qb);
  hipLaunchKernelGGL(k2_kv_reduce, dim3(BH * 4), dim3(256), 0, stream, partial, kvt);
  hipLaunchKernelGGL(k25_u, dim3(BH * 4), dim3(256), 0, stream, W, kvt, Ut);
  hipLaunchKernelGGL(k4_out_gemm, dim3(1024), dim3(256), 0, stream, Qb, Ut, bias, out);
}

// Round 7
// 124.301 us; speedup vs baseline: 1.0024x; 1.0024x over previous
//
#include <hip/hip_runtime.h>
#include <hip/hip_bf16.h>

#define B_ 4
#define S_ 4096
#define DM 1024
#define H_ 16
#define HD 64
#define BH (B_*H_)
#define SPLIT 8
#define CHUNK (S_/SPLIT)   // 512
#define SUB 64             // s-rows per staged buffer

typedef __attribute__((ext_vector_type(8))) __bf16 bf16x8;
typedef __attribute__((ext_vector_type(4))) __bf16 bf16x4;
typedef __attribute__((ext_vector_type(4))) float f32x4;

#define MFMA16(a,b,c) __builtin_amdgcn_mfma_f32_16x16x32_bf16((a),(b),(c),0,0,0)

__device__ __forceinline__ void gload_lds16(const void* g, void* l) {
  __builtin_amdgcn_global_load_lds(
      (const __attribute__((address_space(1))) void*)g,
      (__attribute__((address_space(3))) void*)l, 16, 0, 0);
}

// ---------------------------------------------------------------------------
// K0q: Q f32 -> bf16 streaming cast. 1,048,576 threads x 4 f32x4, stride = #threads.
// ---------------------------------------------------------------------------
__global__ __launch_bounds__(256)
void k0_convq(const float* __restrict__ Qg, __bf16* __restrict__ Qb) {
  const size_t t = (size_t)blockIdx.x * 256 + threadIdx.x;
#pragma unroll
  for (int it = 0; it < 4; ++it) {
    const size_t i = (size_t)it * 1048576 + t;
    f32x4 w = *reinterpret_cast<const f32x4*>(Qg + i * 4);
    bf16x4 o;
#pragma unroll
    for (int j = 0; j < 4; ++j) o[j] = (__bf16)w[j];
    *reinterpret_cast<bf16x4*>(Qb + i * 4) = o;
  }
}

// ---------------------------------------------------------------------------
// K1 v3: partial KV[split][bh][d][e] = sum_s K[s][d]*V[s][e], pure f32 VALU.
// grid = SPLIT*BH = 512 blocks (2/CU), 256 threads.
// NEW: XCD-grouping swizzle — the 16 head-blocks of one (b,split) group all
// get blockIdx ≡ same residue (mod 8) -> same XCD -> rows HBM-fetched once
// into that XCD's L2, 15/16 of reads are L2 hits (was: 8 XCDs x 256-B
// strided re-fetch, ~2.3 TB/s effective).
// ---------------------------------------------------------------------------
__global__ __launch_bounds__(256)
void k1_kv(const float* __restrict__ Kg, const float* __restrict__ Vg,
           float* __restrict__ partial) {
  __shared__ __align__(16) float Kb[2][SUB][64];   // 32 KiB
  __shared__ __align__(16) float Vb[2][SUB][64];   // 32 KiB
  // --- XCD-grouping remap: bid -> (group g on XCD bid&7, head h) ---
  const int bid = blockIdx.x;                 // 0..511, XCD = bid & 7
  const int xcd = bid & 7;
  const int k = bid >> 3;                     // 0..63
  const int h = k & 15;                       // 16 heads per group
  const int g = xcd + (k >> 4) * 8;           // group 0..31 = (b,split)
  const int b = g & 3, split = g >> 2;        // split 0..7
  const int bh = b * 16 + h;
  const int t = threadIdx.x, wid = t >> 6;
  const int s0 = split * CHUNK;
  const float* Ksrc = Kg + ((size_t)b * S_ + s0) * DM + h * HD;
  const float* Vsrc = Vg + ((size_t)b * S_ + s0) * DM + h * HD;
  const int d0 = (t >> 4) * 4, e0 = (t & 15) * 4;
  float acc[4][4] = {};

  auto stage = [&](int bi, int sc) {
    const char* Kp = (const char*)(Ksrc + (size_t)sc * SUB * DM);
    const char* Vp = (const char*)(Vsrc + (size_t)sc * SUB * DM);
#pragma unroll
    for (int it = 0; it < 4; ++it) {
      const int idx = it * 256 + t;
      const int row = idx >> 4, ch = idx & 15;       // 64 rows x 16 chunks(16B)
      const int ldso = (it * 256 + wid * 64) * 16;   // wave-uniform base
      gload_lds16((const void*)(Kp + (size_t)row * (DM * 4) + ch * 16),
                  (void*)((char*)&Kb[bi][0][0] + ldso));
      gload_lds16((const void*)(Vp + (size_t)row * (DM * 4) + ch * 16),
                  (void*)((char*)&Vb[bi][0][0] + ldso));
    }
  };

  stage(0, 0);
  asm volatile("s_waitcnt vmcnt(0)" ::: "memory");
  __builtin_amdgcn_s_barrier();

  for (int hc = 0; hc < CHUNK / SUB; ++hc) {
    const int cur = hc & 1;
    if (hc + 1 < CHUNK / SUB) stage(cur ^ 1, hc + 1);   // prefetch overlaps compute
    const float* Ks = &Kb[cur][0][0];
    const float* Vs = &Vb[cur][0][0];
#pragma unroll 8
    for (int s = 0; s < SUB; ++s) {
      f32x4 kv = *reinterpret_cast<const f32x4*>(Ks + s * 64 + d0);
      f32x4 vv = *reinterpret_cast<const f32x4*>(Vs + s * 64 + e0);
#pragma unroll
      for (int i = 0; i < 4; ++i)
#pragma unroll
        for (int j = 0; j < 4; ++j)
          acc[i][j] = fmaf(kv[i], vv[j], acc[i][j]);
    }
    asm volatile("s_waitcnt vmcnt(0)" ::: "memory");
    __builtin_amdgcn_s_barrier();
  }

  float* dst = partial + ((size_t)(split * BH + bh) << 12);
#pragma unroll
  for (int i = 0; i < 4; ++i) {
    f32x4 o;
#pragma unroll
    for (int j = 0; j < 4; ++j) o[j] = acc[i][j];
    *reinterpret_cast<f32x4*>(dst + (d0 + i) * 64 + e0) = o;
  }
}

// ---------------------------------------------------------------------------
// K2: reduce 8 partials -> kvt[bh][d][e] bf16.  grid = BH*4 = 256 blocks.
// ---------------------------------------------------------------------------
__global__ __launch_bounds__(256)
void k2_kv_reduce(const float* __restrict__ partial,
                  __bf16* __restrict__ kvt) {
  const int bid = blockIdx.x;
  const int bh = bid >> 2, q = bid & 3;
  const int t = threadIdx.x;
#pragma unroll
  for (int i = 0; i < 4; ++i) {
    const int idx = q * 1024 + i * 256 + t;   // d*64+e
    float s = 0.f;
#pragma unroll
    for (int sp = 0; sp < SPLIT; ++sp)
      s += partial[((size_t)(sp * BH + bh) << 12) + idx];
    kvt[((size_t)bh << 12) + idx] = (__bf16)s;
  }
}

// ---------------------------------------------------------------------------
// K2.5: Ut[b][n][h*64+d] = sum_e W[n][h*64+e] * KV[bh][d][e]   (bf16 out)
// grid = BH*4 = 256 blocks.  (unchanged, verified)
// ---------------------------------------------------------------------------
__global__ __launch_bounds__(256)
void k25_u(const float* __restrict__ Wg,
           const __bf16* __restrict__ kvt,
           __bf16* __restrict__ Ut) {
  const int bid = blockIdx.x;
  const int bh = bid >> 2, nblk = bid & 3;
  const int b = bh >> 4, h = bh & 15;
  const int t = threadIdx.x, w = t >> 6, l = t & 63, lr = l & 15, lg = l >> 4;
  const int n0w = nblk * 256 + w * 64;
  const __bf16* kvb = kvt + ((size_t)bh << 12);
  f32x4 acc[4][4] = {};
#pragma unroll
  for (int ks = 0; ks < 2; ++ks) {
    bf16x8 bfr[4];
#pragma unroll
    for (int nf = 0; nf < 4; ++nf)
      bfr[nf] = *reinterpret_cast<const bf16x8*>(kvb + (nf * 16 + lr) * 64 + ks * 32 + lg * 8);
#pragma unroll
    for (int mf = 0; mf < 4; ++mf) {
      const int n = n0w + mf * 16 + lr;
      const float* wp = Wg + (size_t)n * DM + h * 64 + ks * 32 + lg * 8;
      f32x4 w0 = *reinterpret_cast<const f32x4*>(wp);
      f32x4 w1 = *reinterpret_cast<const f32x4*>(wp + 4);
      bf16x8 af;
#pragma unroll
      for (int j = 0; j < 4; ++j) { af[j] = (__bf16)w0[j]; af[4 + j] = (__bf16)w1[j]; }
#pragma unroll
      for (int nf = 0; nf < 4; ++nf)
        acc[mf][nf] = MFMA16(af, bfr[nf], acc[mf][nf]);
    }
  }
  __bf16* ub = Ut + ((size_t)b << 20);
#pragma unroll
  for (int mf = 0; mf < 4; ++mf)
#pragma unroll
    for (int nf = 0; nf < 4; ++nf)
#pragma unroll
      for (int r = 0; r < 4; ++r) {
        const int n = n0w + mf * 16 + lg * 4 + r;
        ub[(size_t)n * DM + h * 64 + nf * 16 + lr] = (__bf16)acc[mf][nf][r];
      }
}

// ---------------------------------------------------------------------------
// K4: out[b] = Qb[b] @ Ut[b]^T + bias.  4 x (M=4096, N=1024, K=1024).
// Both operands bf16 via global_load_lds w16, pre-swizzled source +
// swizzled ds_read_b128 (conflict-free).  (unchanged, verified)
// ---------------------------------------------------------------------------
__global__ __launch_bounds__(256)
void k4_out_gemm(const __bf16* __restrict__ Qb,
                 const __bf16* __restrict__ Ut,
                 const float* __restrict__ biasg,
                 float* __restrict__ outg) {
  __shared__ __align__(16) __bf16 Alds[128 * 64];
  __shared__ __align__(16) __bf16 Blds[128 * 64];
  const int bid = blockIdx.x;
  const int b = bid >> 8, rem = bid & 255;
  const int nblk = rem >> 5, mblk = rem & 31;
  const int m0 = mblk * 128, n0 = nblk * 128;
  const int t = threadIdx.x, wid = t >> 6, l = t & 63, lr = l & 15, lg = l >> 4;
  const int wr = wid >> 1, wc = wid & 1;
  const __bf16* Ab = Qb + (size_t)b * S_ * DM;
  const __bf16* Bb = Ut + ((size_t)b << 20);
  f32x4 acc[4][4] = {};

  for (int kt = 0; kt < 16; ++kt) {
    const int k0 = kt * 64;
#pragma unroll
    for (int it = 0; it < 4; ++it) {
      const int idx = it * 256 + t;
      const int row = idx >> 3, c = idx & 7;
      const int gc = c ^ (row & 7);
      gload_lds16((const void*)(Ab + (size_t)(m0 + row) * DM + k0 + gc * 8),
                  (void*)((char*)Alds + (it * 256 + wid * 64) * 16));
      gload_lds16((const void*)(Bb + (size_t)(n0 + row) * DM + k0 + gc * 8),
                  (void*)((char*)Blds + (it * 256 + wid * 64) * 16));
    }
    __syncthreads();
#pragma unroll
    for (int ks = 0; ks < 2; ++ks) {
      bf16x8 af[4], bfr[4];
#pragma unroll
      for (int mt = 0; mt < 4; ++mt) {
        const int row = wr * 64 + mt * 16 + lr;
        const int ch = (ks * 4 + lg) ^ (row & 7);
        af[mt] = *reinterpret_cast<const bf16x8*>((const char*)Alds + row * 128 + ch * 16);
      }
#pragma unroll
      for (int nt = 0; nt < 4; ++nt) {
        const int row = wc * 64 + nt * 16 + lr;
        const int ch = (ks * 4 + lg) ^ (row & 7);
        bfr[nt] = *reinterpret_cast<const bf16x8*>((const char*)Blds + row * 128 + ch * 16);
      }
#pragma unroll
      for (int mt = 0; mt < 4; ++mt)
#pragma unroll
        for (int nt = 0; nt < 4; ++nt)
          acc[mt][nt] = MFMA16(af[mt], bfr[nt], acc[mt][nt]);
    }
    __syncthreads();
  }

#pragma unroll
  for (int nt = 0; nt < 4; ++nt) {
    const int colg = n0 + wc * 64 + nt * 16 + lr;
    const float bv = biasg[colg];
#pragma unroll
    for (int mt = 0; mt < 4; ++mt)
#pragma unroll
      for (int r = 0; r < 4; ++r) {
        const int rowg = m0 + wr * 64 + mt * 16 + lg * 4 + r;
        outg[((size_t)b * S_ + rowg) * DM + colg] = acc[mt][nt][r] + bv;
      }
  }
}

extern "C" void kernel_launch(void* const* d_in, const int* in_sizes, int n_in,
                              void* d_out, int out_size, void* d_ws, size_t ws_size,
                              hipStream_t stream) {
  const float* Q = (const float*)d_in[0];
  const float* K = (const float*)d_in[1];
  const float* V = (const float*)d_in[2];
  const float* W = (const float*)d_in[3];
  const float* bias = (const float*)d_in[4];
  float* out = (float*)d_out;

  char* ws = (char*)d_ws;
  float* partial = (float*)ws;                        // 8 MiB @ 0
  __bf16* kvt = (__bf16*)(ws + (8u << 20));           // 512 KiB
  __bf16* Ut  = (__bf16*)(ws + (9u << 20));           // 8 MiB
  __bf16* Qb  = (__bf16*)(ws + (17u << 20));          // 32 MiB

  hipLaunchKernelGGL(k1_kv, dim3(SPLIT * BH), dim3(256), 0, stream, K, V, partial);
  hipLaunchKernelGGL(k0_convq, dim3(4096), dim3(256), 0, stream, Q, Qb);
  hipLaunchKernelGGL(k2_kv_reduce, dim3(BH * 4), dim3(256), 0, stream, partial, kvt);
  hipLaunchKernelGGL(k25_u, dim3(BH * 4), dim3(256), 0, stream, W, kvt, Ut);
  hipLaunchKernelGGL(k4_out_gemm, dim3(1024), dim3(256), 0, stream, Qb, Ut, bias, out);
}